// Round 6
// baseline (449.574 us; speedup 1.0000x reference)
//
#include <hip/hip_runtime.h>
#include <math.h>

// Problem constants (from reference setup_inputs)
#define BATCH 32
#define NPTS  4096
#define DCH   254            // input channels; output row = DCH + 2 = 256
#define OUTC  256
#define PB    64             // partial-reduce chunks per batch
#define NBLK1 (BATCH * PB)   // 2048 reduce blocks
#define EPSV  1e-5f

#define BFLOATS (NPTS * DCH)     // 1,040,384 floats per batch
#define B4      (BFLOATS / 4)    // 260,096 float4 per batch (batch base 16B-aligned)
#define C4      (B4 / PB)        // 4,064 float4 per chunk (= 64 rows)

#define NORM_BLOCKS 4096         // 32 rows/block, 128 blocks per batch
#define ROWS_PER_BLK2 (BATCH * NPTS / NORM_BLOCKS)   // 32

// MEASUREMENT ROUND: internal repeats (idempotent) push both kernels past the
// ~79us fill-dispatch threshold so they surface in rocprof's top-5 WITH
// FETCH/WRITE counters. asm memory clobbers between reps defeat CSE/DSE.
#define RRED 6                   // reduce sweeps x 6x
#define RNRM 4                   // norm does its load/fma/store pass 4x

// ---------------------------------------------------------------------------
// Kernel 1: per-batch partial reduction, contiguous chunks, repeated RRED x.
// FETCH_SIZE tells us whether reps 2..6 are served by L3 (~140 MB) or HBM (~800 MB).
// ---------------------------------------------------------------------------
__global__ __launch_bounds__(256) void ipn_reduce(const float* __restrict__ x,
                                                  float2* __restrict__ partials) {
    const int blk = blockIdx.x;
    const int b   = blk / PB;
    const int j   = blk % PB;
    const float4* xb = (const float4*)(x + (size_t)b * BFLOATS);
    const int i0 = j * C4;
    __shared__ float ls[4], lss[4];
    const int wv = threadIdx.x >> 6;

    for (int rep = 0; rep < RRED; ++rep) {
        float s = 0.f, ss = 0.f;
        for (int i = i0 + threadIdx.x; i < i0 + C4; i += 256) {   // 15-16 iters
            float4 v = xb[i];
            s  += (v.x + v.y) + (v.z + v.w);
            ss += (v.x * v.x + v.y * v.y) + (v.z * v.z + v.w * v.w);
        }
        #pragma unroll
        for (int off = 32; off > 0; off >>= 1) {
            s  += __shfl_down(s, off);
            ss += __shfl_down(ss, off);
        }
        if ((threadIdx.x & 63) == 0) { ls[wv] = s; lss[wv] = ss; }
        __syncthreads();
        if (threadIdx.x == 0) {
            partials[blk] = make_float2((ls[0]  + ls[1])  + (ls[2]  + ls[3]),
                                        (lss[0] + lss[1]) + (lss[2] + lss[3]));
        }
        __syncthreads();                       // protect ls/lss reuse next rep
        asm volatile("" ::: "memory");         // force real reloads next rep
    }
}

// ---------------------------------------------------------------------------
// Kernel 2: finalize + normalize + concat + scale/bias, row-pass repeated RNRM x.
// FETCH_SIZE tells us whether the x re-read under 134 MB/rep of write pressure
// is L3-served (~<150 MB) or HBM (~500 MB). WRITE_SIZE shows rewrite coalescing.
// ---------------------------------------------------------------------------
__global__ __launch_bounds__(256) void ipn_norm(const float* __restrict__ x,
                                                const float* __restrict__ w,
                                                const float* __restrict__ bias,
                                                const float2* __restrict__ partials,
                                                float* __restrict__ out) {
    const int lane = threadIdx.x & 63;
    const int wv   = threadIdx.x >> 6;
    const int b    = blockIdx.x >> 7;          // 128 blocks per batch

    // ---- fold this batch's 64 partials (each wave redundantly, in-register) ----
    float2 p = partials[b * PB + lane];
    float S = p.x, SS = p.y;
    #pragma unroll
    for (int off = 32; off > 0; off >>= 1) {
        S  += __shfl_xor(S, off);
        SS += __shfl_xor(SS, off);
    }
    const float invM = 1.0f / (float)BFLOATS;
    const float mean = S * invM;
    const float var  = fmaxf(SS * invM - mean * mean, 0.f);
    const float stdv = sqrtf(var);
    const float inv  = 1.0f / (stdv + EPSV);

    // ---- per-lane fused scale/offset: out = v*(inv*w) + (b - mean*inv*w) ----
    const int c0 = lane * 4;
    const float4 w4 = ((const float4*)w)[lane];
    const float4 b4 = ((const float4*)bias)[lane];
    float4 s4, o4;
    s4.x = inv * w4.x;  o4.x = b4.x - mean * s4.x;
    s4.y = inv * w4.y;  o4.y = b4.y - mean * s4.y;
    s4.z = inv * w4.z;  o4.z = b4.z - mean * s4.z;
    s4.w = inv * w4.w;  o4.w = b4.w - mean * s4.w;
    const float oz63 = mean * w4.z + b4.z;     // col 254 = mean (scaled/biased)
    const float ow63 = stdv * w4.w + b4.w;     // col 255 = std

    const int row0 = blockIdx.x * ROWS_PER_BLK2;

    for (int rep = 0; rep < RNRM; ++rep) {
        for (int r = wv; r < ROWS_PER_BLK2; r += 4) {
            const int row = row0 + r;
            const float* xr = x + (size_t)row * DCH + c0;
            const float2 lo = *(const float2*)xr;            // cols c0, c0+1
            float4 o;
            o.x = lo.x * s4.x + o4.x;
            o.y = lo.y * s4.y + o4.y;
            if (c0 < 252) {
                const float2 hi = *(const float2*)(xr + 2);  // cols c0+2, c0+3
                o.z = hi.x * s4.z + o4.z;
                o.w = hi.y * s4.w + o4.w;
            } else {                                          // lane 63
                o.z = oz63;
                o.w = ow63;
            }
            ((float4*)(out + (size_t)row * OUTC))[lane] = o;
        }
        asm volatile("" ::: "memory");         // keep reps observable (no CSE/DSE)
    }
}

// ---------------------------------------------------------------------------
extern "C" void kernel_launch(void* const* d_in, const int* in_sizes, int n_in,
                              void* d_out, int out_size, void* d_ws, size_t ws_size,
                              hipStream_t stream) {
    const float* x   = (const float*)d_in[0];   // [32, 4096, 254] fp32
    const float* wgt = (const float*)d_in[1];   // [256] fp32
    const float* bia = (const float*)d_in[2];   // [256] fp32
    float* out       = (float*)d_out;           // [32, 4096, 256] fp32

    float2* partials = (float2*)d_ws;           // 2048 * 8 B = 16 KB

    ipn_reduce<<<NBLK1, 256, 0, stream>>>(x, partials);
    ipn_norm<<<NORM_BLOCKS, 256, 0, stream>>>(x, wgt, bia, partials, out);
}

// Round 8
// 258.002 us; speedup vs baseline: 1.7425x; 1.7425x over previous
//
#include <hip/hip_runtime.h>
#include <math.h>

// Problem constants (from reference setup_inputs)
#define BATCH 32
#define NPTS  4096
#define DCH   254            // input channels; output row = DCH + 2 = 256
#define OUTC  256
#define PB    64             // partial-reduce chunks per batch
#define NBLK1 (BATCH * PB)   // 2048 reduce blocks
#define EPSV  1e-5f

#define BFLOATS (NPTS * DCH)     // 1,040,384 floats per batch
#define B4      (BFLOATS / 4)    // 260,096 float4 per batch (batch base 16B-aligned)
#define C4      (B4 / PB)        // 4,064 float4 per chunk (= 64 rows)

#define NORM_BLOCKS 4096         // 32 rows/block, 128 blocks per batch
#define ROWS_PER_BLK2 (BATCH * NPTS / NORM_BLOCKS)   // 32

// ---------------------------------------------------------------------------
// RESTORATION ROUND: byte-identical to the round-5 artifact (passed, 255.35us).
// The round-7 fused spin-kernel deadlocked the device (inter-block spin under
// a plain launch depends on dispatch order/co-residency -- G16 violation).
// Session accounting: fixed harness ~210us, reduce ~22us, norm ~23us vs a
// ~40us mandatory-traffic floor (133 MB read + 134 MB write, re-read L3-hit).
// ---------------------------------------------------------------------------

// ---------------------------------------------------------------------------
// Kernel 1: per-batch partial reduction, contiguous chunks (ascending sweep).
// Grid = 2048 blocks x 256 threads -> all blocks co-resident, HBM-BW-bound.
// Every partials slot is written unconditionally (0xAA-poisoned ws needs no init).
// ---------------------------------------------------------------------------
__global__ __launch_bounds__(256) void ipn_reduce(const float* __restrict__ x,
                                                  float2* __restrict__ partials) {
    const int blk = blockIdx.x;
    const int b   = blk / PB;
    const int j   = blk % PB;
    const float4* xb = (const float4*)(x + (size_t)b * BFLOATS);

    float s = 0.f, ss = 0.f;
    const int i0 = j * C4;
    for (int i = i0 + threadIdx.x; i < i0 + C4; i += 256) {   // C4=4064: 15-16 iters
        float4 v = xb[i];
        s  += (v.x + v.y) + (v.z + v.w);
        ss += (v.x * v.x + v.y * v.y) + (v.z * v.z + v.w * v.w);
    }
    #pragma unroll
    for (int off = 32; off > 0; off >>= 1) {
        s  += __shfl_down(s, off);
        ss += __shfl_down(ss, off);
    }
    __shared__ float ls[4], lss[4];
    const int wv = threadIdx.x >> 6;
    if ((threadIdx.x & 63) == 0) { ls[wv] = s; lss[wv] = ss; }
    __syncthreads();
    if (threadIdx.x == 0) {
        partials[blk] = make_float2((ls[0]  + ls[1])  + (ls[2]  + ls[3]),
                                    (lss[0] + lss[1]) + (lss[2] + lss[3]));
    }
}

// ---------------------------------------------------------------------------
// Kernel 2: finalize (folded in) + normalize + concat(mean,std) + scale/bias.
// Grid = 4096 blocks x 256 threads; block handles 32 rows of ONE batch,
// one wave per 256-col output row, 8 rows per wave.
// ---------------------------------------------------------------------------
__global__ __launch_bounds__(256) void ipn_norm(const float* __restrict__ x,
                                                const float* __restrict__ w,
                                                const float* __restrict__ bias,
                                                const float2* __restrict__ partials,
                                                float* __restrict__ out) {
    const int lane = threadIdx.x & 63;
    const int wv   = threadIdx.x >> 6;
    const int rblk = (NORM_BLOCKS - 1) - blockIdx.x;   // reversed mapping (neutral)
    const int b    = rblk >> 7;                        // 128 blocks per batch

    // ---- fold this batch's 64 partials (each wave redundantly, in-register) ----
    float2 p = partials[b * PB + lane];
    float S = p.x, SS = p.y;
    #pragma unroll
    for (int off = 32; off > 0; off >>= 1) {   // butterfly: every lane gets totals
        S  += __shfl_xor(S, off);
        SS += __shfl_xor(SS, off);
    }
    const float invM = 1.0f / (float)BFLOATS;
    const float mean = S * invM;
    const float var  = fmaxf(SS * invM - mean * mean, 0.f);   // biased variance
    const float stdv = sqrtf(var);
    const float inv  = 1.0f / (stdv + EPSV);

    // ---- per-lane fused scale/offset: out = v*(inv*w) + (b - mean*inv*w) ----
    const int c0 = lane * 4;
    const float4 w4 = ((const float4*)w)[lane];
    const float4 b4 = ((const float4*)bias)[lane];
    float4 s4, o4;
    s4.x = inv * w4.x;  o4.x = b4.x - mean * s4.x;
    s4.y = inv * w4.y;  o4.y = b4.y - mean * s4.y;
    s4.z = inv * w4.z;  o4.z = b4.z - mean * s4.z;
    s4.w = inv * w4.w;  o4.w = b4.w - mean * s4.w;
    // lane 63 splice constants (cols 254=mean, 255=std), batch-invariant
    const float oz63 = mean * w4.z + b4.z;
    const float ow63 = stdv * w4.w + b4.w;

    const int row0 = rblk * ROWS_PER_BLK2;

    for (int r = wv; r < ROWS_PER_BLK2; r += 4) {
        const int row = row0 + r;
        const float* xr = x + (size_t)row * DCH + c0;
        const float2 lo = *(const float2*)xr;            // cols c0, c0+1
        float4 o;
        o.x = lo.x * s4.x + o4.x;
        o.y = lo.y * s4.y + o4.y;
        if (c0 < 252) {
            const float2 hi = *(const float2*)(xr + 2);  // cols c0+2, c0+3
            o.z = hi.x * s4.z + o4.z;
            o.w = hi.y * s4.w + o4.w;
        } else {                                          // lane 63
            o.z = oz63;
            o.w = ow63;
        }
        ((float4*)(out + (size_t)row * OUTC))[lane] = o;
    }
}

// ---------------------------------------------------------------------------
extern "C" void kernel_launch(void* const* d_in, const int* in_sizes, int n_in,
                              void* d_out, int out_size, void* d_ws, size_t ws_size,
                              hipStream_t stream) {
    const float* x   = (const float*)d_in[0];   // [32, 4096, 254] fp32
    const float* wgt = (const float*)d_in[1];   // [256] fp32
    const float* bia = (const float*)d_in[2];   // [256] fp32
    float* out       = (float*)d_out;           // [32, 4096, 256] fp32

    float2* partials = (float2*)d_ws;           // 2048 * 8 B = 16 KB

    ipn_reduce<<<NBLK1, 256, 0, stream>>>(x, partials);
    ipn_norm<<<NORM_BLOCKS, 256, 0, stream>>>(x, wgt, bia, partials, out);
}